// Round 13
// baseline (134.728 us; speedup 1.0000x reference)
//
#include <hip/hip_runtime.h>

// MoE: out[b,:] = sum_e softmax(gate(x))[b,e] * (W3_e^T @ relu(W2_e^T @ relu(W1_e^T @ x_b + b1) + b2) + b3)
// R21: STAGE-BATCHED dataflow on the verified 32x32x16 base (R17 layout, absmax 0.0156).
//      Ledger R12-R20: spills fixed; TLP>2, ILP-width, prefetch, tile-size, tile-interleave,
//      SGB forced-schedule ALL null; per-token SIMD floor invariant at ~134-136 cyc across 3
//      structures; pipe shares MFMA 31 + VALU 37 + DS 11 ~= 80% sum, none saturated ->
//      per-wave stage serialization (MFMA->pack->MFMA latency exposed at every boundary).
//      Fix: process experts in BATCHES OF 4 with phase-ordered program text:
//        A: 4 independent L1 MFMAs back-to-back (128 cyc pipe distance)
//        B: all 4 experts' packs (producers >=128 cyc upstream -> latency hidden)
//        C: 8 L2 MFMAs back-to-back   D: packs (+b2 packed-f16 add)   E: 8 L3 MFMAs -> Ya/Yb
//      b2 as packed-h2 LDS image (b2pk) frees the 64 f32 C-init regs so 4 chains fit the
//      proven (2,2) caps (128 arch + 128 acc): est. peak ~110 arch / ~96 acc, zero spills.
//      Guards: WRITE_SIZE stays 8.19 MB, VGPR <= 128, absmax <= 0.0156. Null => declare
//      structural floor (all source-level DoF measured).

typedef _Float16 half2_t __attribute__((ext_vector_type(2)));
typedef _Float16 half8_t __attribute__((ext_vector_type(8)));
typedef __fp16   fp16v2  __attribute__((ext_vector_type(2)));
typedef float  f32x16   __attribute__((ext_vector_type(16)));
typedef float  float4_t __attribute__((ext_vector_type(4)));
typedef float  float2_t __attribute__((ext_vector_type(2)));
typedef int    int4_t   __attribute__((ext_vector_type(4)));

#define MFMA32(A, B, C) __builtin_amdgcn_mfma_f32_32x32x16_f16((A), (B), (C), 0, 0, 0)

static constexpr int E_ = 8, DIN_ = 6, H_ = 32, EB_ = 4;   // expert batch size

union H8U { half2_t h2[4]; half8_t h8; int4_t i4; };
union HI  { half2_t h; int i; };
union PKU { fp16v2 p; half2_t h; };
union C16 { f32x16 v; float4_t q[4]; };

__device__ __forceinline__ half2_t pkrtz(float a, float b) {
    PKU u; u.p = __builtin_amdgcn_cvt_pkrtz(a, b);
    return u.h;
}

__device__ __forceinline__ half2_t relu2(half2_t v) {
    const half2_t z = {(_Float16)0.0f, (_Float16)0.0f};
    return __builtin_elementwise_max(v, z);
}

__global__ __launch_bounds__(256)
__attribute__((amdgpu_waves_per_eu(2, 2)))
void moe_kernel(
    const float* __restrict__ x,  const float* __restrict__ W1, const float* __restrict__ b1,
    const float* __restrict__ W2, const float* __restrict__ b2, const float* __restrict__ W3,
    const float* __restrict__ b3, const float* __restrict__ Wg1, const float* __restrict__ bg1,
    const float* __restrict__ Wg2, const float* __restrict__ bg2,
    float* __restrict__ out, int nTok, int nTiles, int tilesPerWave)
{
    const int tid  = threadIdx.x;
    const int lane = tid & 63;
    const int m    = lane & 31;   // A-row / token-column index
    const int h    = lane >> 5;   // lane half: K sub-block selector
    const int wv   = tid >> 6;    // wave in block
    const int gw   = (blockIdx.x << 2) + wv;   // global wave id (waves independent)

    __shared__ H8U w1img[E_][64];        //  8 KB: L1 A-frag (k=features, bias at k=6)
    __shared__ H8U w2img[E_][2][64];     // 16 KB: L2 A-frag, K-blocks lo/hi
    __shared__ H8U a3img[E_][2][64];     // 16 KB: L3 A-frag, block-diag rows m=2e+o, zeros baked
    __shared__ int4_t b2pk[E_][2][2];    // 512 B: packed-h2 b2 per (e,h): [0]=c2 regs0-7 [1]=8-15
    __shared__ H8U g1s[64];              //  1 KB: gate L1 A-frag
    __shared__ H8U g2s[2][64];           //  2 KB: gate L2 A-frag, K-blocks
    __shared__ __align__(16) float b3s[16];       // b3 rows (Y C-init; row index == b3 index)
    __shared__ __align__(16) float bg2s[8];       // bg2 * log2e (gate C-init rows 0..7)

    const float L2E = 1.44269504f;
    const half2_t h2z = pkrtz(0.f, 0.f);

    // ---- build expert images: wave wv packs experts {2wv, 2wv+1} (layout verified R17)
    #pragma unroll
    for (int j = 0; j < 2; ++j) {
        const int e = wv * 2 + j;
        H8U w1v;
        if (h == 0) {
            w1v.h2[0] = pkrtz(W1[(e*DIN_+0)*H_+m], W1[(e*DIN_+1)*H_+m]);
            w1v.h2[1] = pkrtz(W1[(e*DIN_+2)*H_+m], W1[(e*DIN_+3)*H_+m]);
        } else {
            w1v.h2[0] = pkrtz(W1[(e*DIN_+4)*H_+m], W1[(e*DIN_+5)*H_+m]);
            w1v.h2[1] = pkrtz(b1[e*H_+m], 0.f);          // k=6 bias slot; k=7 zero
        }
        w1v.h2[2] = h2z; w1v.h2[3] = h2z;                // k>=8 zero
        w1img[e][lane] = w1v;

        const int o = m & 1;
        const bool alive = ((m >> 1) == e);              // rows m=2e+o only (m<16)
        #pragma unroll
        for (int b = 0; b < 2; ++b) {
            H8U w2v, a3v;
            #pragma unroll
            for (int p = 0; p < 4; ++p) {
                const int k0 = 16*b + 8*(p>>1) + 4*h + 2*(p&1);
                w2v.h2[p] = pkrtz(W2[(e*H_+k0)*H_+m], W2[(e*H_+k0+1)*H_+m]);
                a3v.h2[p] = alive ? pkrtz(W3[(e*H_+k0)*2+o], W3[(e*H_+k0+1)*2+o]) : h2z;
            }
            w2img[e][b][lane] = w2v;
            a3img[e][b][lane] = a3v;
        }
        // packed b2 for this h: c2 reg r -> row (r&3)+8*(r>>2)+4h (+16 for regs 8-15)
        H8U b2lo, b2hi;
        #pragma unroll
        for (int p = 0; p < 4; ++p) {
            const int r0 = 2*p, r1 = 2*p + 1;
            const int rr0 = (r0&3) + 8*(r0>>2) + 4*h;
            const int rr1 = (r1&3) + 8*(r1>>2) + 4*h;
            b2lo.h2[p] = pkrtz(b2[e*H_ + rr0],      b2[e*H_ + rr1]);
            b2hi.h2[p] = pkrtz(b2[e*H_ + 16 + rr0], b2[e*H_ + 16 + rr1]);
        }
        b2pk[e][h][0] = b2lo.i4;   // same-address same-value writes across the h-group: benign
        b2pk[e][h][1] = b2hi.i4;
    }

    // ---- wave 0 builds gate images + bias tables
    if (wv == 0) {
        H8U g1v;
        if (h == 0) {
            g1v.h2[0] = pkrtz(Wg1[0*H_+m], Wg1[1*H_+m]);
            g1v.h2[1] = pkrtz(Wg1[2*H_+m], Wg1[3*H_+m]);
        } else {
            g1v.h2[0] = pkrtz(Wg1[4*H_+m], Wg1[5*H_+m]);
            g1v.h2[1] = pkrtz(bg1[m], 0.f);
        }
        g1v.h2[2] = h2z; g1v.h2[3] = h2z;
        g1s[lane] = g1v;

        const bool alive = (m < E_);                     // logits rows 0..7 only
        #pragma unroll
        for (int b = 0; b < 2; ++b) {
            H8U g2v;
            #pragma unroll
            for (int p = 0; p < 4; ++p) {
                const int k0 = 16*b + 8*(p>>1) + 4*h + 2*(p&1);
                g2v.h2[p] = alive ? pkrtz(Wg2[k0*E_+m]*L2E, Wg2[(k0+1)*E_+m]*L2E) : h2z;
            }
            g2s[b][lane] = g2v;
        }
        if (lane < 16) b3s[lane] = b3[lane];
        if (lane < E_) bg2s[lane] = bg2[lane] * L2E;
    }

    const f32x16 z16 = {0,0,0,0, 0,0,0,0, 0,0,0,0, 0,0,0,0};
    const float4_t z4 = {0.f, 0.f, 0.f, 0.f};

    __syncthreads();   // images ready; NO barriers inside the loop

    const int tile0 = gw * tilesPerWave;
    const int xo1 = h ? 4 : 0;
    const int xo2 = h ? 4 : 2;
    const float* xq = x + ((size_t)tile0 * 32 + m) * DIN_;
    float2_t la = {0.f, 0.f}, lb = {0.f, 0.f};
    if (tile0 < nTiles && (size_t)tile0 * 32 + m < (size_t)nTok) {
        la = *(const float2_t*)(xq + xo1);
        lb = *(const float2_t*)(xq + xo2);
    }
    HI onei; onei.h = pkrtz(1.f, 0.f);

    // ---- main loop: one 32-token tile; experts in STAGE-BATCHED groups of 4
    for (int it = 0; it < tilesPerWave; ++it) {
        const int tile = tile0 + it;
        if (tile >= nTiles) break;          // uniform per wave
        const bool tok = ((size_t)tile * 32 + m) < (size_t)nTok;

        // per-iter volatile reads (must not be hoisted into persistent registers)
        H8U g1v;  g1v.i4  = *(const volatile int4_t*)&g1s[lane].i4;
        H8U g2v0; g2v0.i4 = *(const volatile int4_t*)&g2s[0][lane].i4;
        H8U g2v1; g2v1.i4 = *(const volatile int4_t*)&g2s[1][lane].i4;
        float4_t bgq  = *(const volatile float4_t*)&bg2s[4*h];
        float4_t b3q0 = *(const volatile float4_t*)&b3s[4*h];        // Ya regs 0-3 rows 4h+r
        float4_t b3q1 = *(const volatile float4_t*)&b3s[8 + 4*h];    // Ya regs 4-7 rows 8+4h+r

        // x B-frag: h=0: {x0..x3, 0..}; h=1: {x4,x5,1,0, 0..}
        H8U xB;
        xB.h2[0] = pkrtz(la[0], la[1]);
        { HI hb; hb.h = pkrtz(lb[0], lb[1]); HI se; se.i = h ? onei.i : hb.i; xB.h2[1] = se.h; }
        xB.h2[2] = h2z; xB.h2[3] = h2z;

        // prefetch next tile's x
        if (it + 1 < tilesPerWave && tile + 1 < nTiles) {
            const float* xn = xq + (size_t)(it + 1) * 32 * DIN_;
            if ((size_t)(tile + 1) * 32 + m < (size_t)nTok) {
                la = *(const float2_t*)(xn + xo1);
                lb = *(const float2_t*)(xn + xo2);
            }
        }

        // ---- gate: 3 MFMAs; logits rows 4h+0..3 = experts 4h+0..3
        f32x16 hg = MFMA32(g1v.h8, xB.h8, z16);
        H8U uhlo, uhhi;
        #pragma unroll
        for (int i = 0; i < 4; ++i) {
            uhlo.h2[i] = relu2(pkrtz(hg[2*i],   hg[2*i+1]));
            uhhi.h2[i] = relu2(pkrtz(hg[8+2*i], hg[8+2*i+1]));
        }
        C16 gc; gc.q[0] = bgq; gc.q[1] = z4; gc.q[2] = z4; gc.q[3] = z4;
        f32x16 gl = MFMA32(g2v0.h8, uhlo.h8, gc.v);
        gl = MFMA32(g2v1.h8, uhhi.h8, gl);

        // softmax over 8 experts (log2 domain; no max-sub), normalization deferred
        float ex0 = __builtin_amdgcn_exp2f(gl[0]);
        float ex1 = __builtin_amdgcn_exp2f(gl[1]);
        float ex2 = __builtin_amdgcn_exp2f(gl[2]);
        float ex3 = __builtin_amdgcn_exp2f(gl[3]);
        float s = (ex0 + ex1) + (ex2 + ex3);
        s += __shfl_xor(s, 32);
        float rs = __builtin_amdgcn_rcpf(s);
        float sA = h ? ex0 : ex2, sB = h ? ex1 : ex3;
        HI sp; sp.h = pkrtz(sA, sB);
        HI rp; rp.i = __shfl_xor(sp.i, 32);
        float rA = (float)rp.h[0], rB = (float)rp.h[1];
        float wA = h ? rA : ex0, wB = h ? rB : ex1;
        float wC = h ? ex2 : rA, wD = h ? ex3 : rB;

        // ---- experts: 2 stage-batched groups of 4; phases A-E per group
        f32x16 Ya, Yb;
        { C16 yc; yc.q[0] = b3q0; yc.q[1] = b3q1; yc.q[2] = z4; yc.q[3] = z4; Ya = yc.v; }
        Yb = z16;
        #pragma unroll
        for (int bb = 0; bb < 2; ++bb) {
            const int eb = bb * EB_;

            // L1 weights, then Phase A: 4 independent L1 MFMAs back-to-back
            H8U a1[EB_];
            #pragma unroll
            for (int j = 0; j < EB_; ++j) a1[j].i4 = w1img[eb + j][lane].i4;
            f32x16 c1[EB_];
            #pragma unroll
            for (int j = 0; j < EB_; ++j) c1[j] = MFMA32(a1[j].h8, xB.h8, z16);

            // L2 weights issue here (latency covered by Phase B packs)
            H8U a2lo[EB_], a2hi[EB_];
            #pragma unroll
            for (int j = 0; j < EB_; ++j) {
                a2lo[j].i4 = w2img[eb + j][0][lane].i4;
                a2hi[j].i4 = w2img[eb + j][1][lane].i4;
            }

            // Phase B: all packs (producers are >=4 MFMAs upstream)
            H8U u1lo[EB_], u1hi[EB_];
            #pragma unroll
            for (int j = 0; j < EB_; ++j)
                #pragma unroll
                for (int i = 0; i < 4; ++i) {
                    u1lo[j].h2[i] = relu2(pkrtz(c1[j][2*i],   c1[j][2*i+1]));
                    u1hi[j].h2[i] = relu2(pkrtz(c1[j][8+2*i], c1[j][8+2*i+1]));
                }

            // Phase C: 8 L2 MFMAs back-to-back
            f32x16 c2[EB_];
            #pragma unroll
            for (int j = 0; j < EB_; ++j) c2[j] = MFMA32(a2lo[j].h8, u1lo[j].h8, z16);
            #pragma unroll
            for (int j = 0; j < EB_; ++j) c2[j] = MFMA32(a2hi[j].h8, u1hi[j].h8, c2[j]);

            // b2 + L3 weights issue here (latency covered by Phase D packs)
            H8U b2l[EB_], b2h[EB_], a3lo[EB_], a3hi[EB_];
            #pragma unroll
            for (int j = 0; j < EB_; ++j) {
                b2l[j].i4  = *(const int4_t*)&b2pk[eb + j][h][0];
                b2h[j].i4  = *(const int4_t*)&b2pk[eb + j][h][1];
                a3lo[j].i4 = a3img[eb + j][0][lane].i4;
                a3hi[j].i4 = a3img[eb + j][1][lane].i4;
            }

            // Phase D: all packs + b2 (packed-h2 add) + relu
            H8U u2lo[EB_], u2hi[EB_];
            #pragma unroll
            for (int j = 0; j < EB_; ++j)
                #pragma unroll
                for (int i = 0; i < 4; ++i) {
                    u2lo[j].h2[i] = relu2(pkrtz(c2[j][2*i],   c2[j][2*i+1])   + b2l[j].h2[i]);
                    u2hi[j].h2[i] = relu2(pkrtz(c2[j][8+2*i], c2[j][8+2*i+1]) + b2h[j].h2[i]);
                }

            // Phase E: 8 L3 MFMAs; alternate Ya/Yb to halve the accumulate chain
            #pragma unroll
            for (int j = 0; j < EB_; ++j) {
                if (j & 1) {
                    Yb = MFMA32(a3lo[j].h8, u2lo[j].h8, Yb);
                    Yb = MFMA32(a3hi[j].h8, u2hi[j].h8, Yb);
                } else {
                    Ya = MFMA32(a3lo[j].h8, u2lo[j].h8, Ya);
                    Ya = MFMA32(a3hi[j].h8, u2hi[j].h8, Ya);
                }
            }
        }

        // ---- epilogue: Y regs 0-7 = rows {4h..4h+3, 8+4h..+3} = (e,o); b3 already in Ya
        float p0 = wA*(Ya[0]+Yb[0]) + wB*(Ya[2]+Yb[2]) + wC*(Ya[4]+Yb[4]) + wD*(Ya[6]+Yb[6]);
        float p1 = wA*(Ya[1]+Yb[1]) + wB*(Ya[3]+Yb[3]) + wC*(Ya[5]+Yb[5]) + wD*(Ya[7]+Yb[7]);
        p0 += __shfl_xor(p0, 32);
        p1 += __shfl_xor(p1, 32);
        if (h == 0 && tok) {
            float2_t ov = {p0 * rs, p1 * rs};
            *(float2_t*)(out + ((size_t)tile * 32 + m) * 2) = ov;
        }
    }
}

extern "C" void kernel_launch(void* const* d_in, const int* in_sizes, int n_in,
                              void* d_out, int out_size, void* d_ws, size_t ws_size,
                              hipStream_t stream) {
    const float* x   = (const float*)d_in[0];
    const float* W1  = (const float*)d_in[1];
    const float* b1  = (const float*)d_in[2];
    const float* W2  = (const float*)d_in[3];
    const float* b2  = (const float*)d_in[4];
    const float* W3  = (const float*)d_in[5];
    const float* b3  = (const float*)d_in[6];
    const float* Wg1 = (const float*)d_in[7];
    const float* bg1 = (const float*)d_in[8];
    const float* Wg2 = (const float*)d_in[9];
    const float* bg2 = (const float*)d_in[10];
    float* out = (float*)d_out;

    const int B      = in_sizes[0] / DIN_;
    const int nTiles = (B + 31) / 32;
    // waves_per_eu(2,2): 128 arch + 128 acc (proven). 512 blocks x 4 waves = 2048 waves =
    // exact 2 waves/SIMD; ~44 KB LDS x 2 blocks/CU <= 160 KB. 32768 tiles / 2048 waves =
    // 16 tiles/wave, zero tail at B=1M.
    const int blocks = 512;
    const int wavesTotal = blocks * 4;
    const int tpw = (nTiles + wavesTotal - 1) / wavesTotal;

    moe_kernel<<<blocks, 256, 0, stream>>>(x, W1, b1, W2, b2, W3, b3,
                                           Wg1, bg1, Wg2, bg2, out, B, nTiles, tpw);
}

// Round 14
// 130.853 us; speedup vs baseline: 1.0296x; 1.0296x over previous
//
#include <hip/hip_runtime.h>

// MoE: out[b,:] = sum_e softmax(gate(x))[b,e] * (W3_e^T @ relu(W2_e^T @ relu(W1_e^T @ x_b + b1) + b2) + b3)
// Tokens-as-N MFMA. L1 uses 16x16x16 f16 (K=7 useful, k=4q+j). L2/L3/gate-L2 use 16x16x32 f16
// with K-permutation pi(q*8+j)=q*4+(j&3)+16*(j>>2) so C/D layout == next layer's B layout
// in-lane (HW-verified across R2-R21: absmax 0.0156).
// R22: REVERT to R16 -- the best-measured kernel of the session (55.9-56.6 us/dispatch,
//      VGPR 68, zero spills). Final ledger across R12-R21: spills fixed (2x); TLP 1->2 =
//      1.95x; TLP 2->3, ILP-width, load-pipelining, 32-token tiles, tile-interleave, SGB
//      forced-schedule all NULL; stage-batching NEGATIVE (reg-file traffic). Seven kernels
//      land in a 56-58 us band at an invariant ~135 SIMD-cyc/token with MFMA 31% + VALU 40%
//      + DS 11% and no pipe saturated: a dependent-chain (MFMA->pack->MFMA) latency floor
//      that no source-level lever penetrates on this toolchain. This round validates
//      reproduction of the floor artifact; structure: 3 waves/SIMD (waves_per_eu(3,3), arch
//      cap ~85 under the proven even arch/acc split), LDS weight images, b2 as f32 C-init,
//      TB=2, expert-loop software pipeline, no loop barriers.

typedef _Float16 half2_t __attribute__((ext_vector_type(2)));
typedef _Float16 half4_t __attribute__((ext_vector_type(4)));
typedef _Float16 half8_t __attribute__((ext_vector_type(8)));
typedef __fp16   fp16v2  __attribute__((ext_vector_type(2)));
typedef float  float4_t __attribute__((ext_vector_type(4)));
typedef float  float2_t __attribute__((ext_vector_type(2)));
typedef int    int2_t   __attribute__((ext_vector_type(2)));
typedef int    int4_t   __attribute__((ext_vector_type(4)));

#define MFMA_K32(A, B, C) __builtin_amdgcn_mfma_f32_16x16x32_f16((A), (B), (C), 0, 0, 0)
#define MFMA_K16(A, B, C) __builtin_amdgcn_mfma_f32_16x16x16f16((A), (B), (C), 0, 0, 0)

static constexpr int E_ = 8, DIN_ = 6, H_ = 32, TB_ = 2;   // tiles per iteration

union H8U { half2_t h2[4]; half8_t h8; int4_t i4; };
union H4U { half2_t h2[2]; half4_t h4; int2_t i2; };
union W1U { H4U f[2]; int4_t i4; };    // 16B: both L1 A-fragments (or both gate-L1 frags)
union HI  { half2_t h; int i; };
union PKU { fp16v2 p; half2_t h; };

__device__ __forceinline__ half2_t pkrtz(float a, float b) {
    PKU u; u.p = __builtin_amdgcn_cvt_pkrtz(a, b);
    return u.h;
}

__device__ __forceinline__ half2_t relu2(half2_t v) {
    const half2_t z = {(_Float16)0.0f, (_Float16)0.0f};
    return __builtin_elementwise_max(v, z);
}

// full gate chain for one tile: logits (log2 domain) -> ex weights for this lane's expert
// pair {2q,2q+1} + deferred-normalization reciprocal (valid in quads 0-1)
__device__ __forceinline__ void gate_eval(
    half4_t xB, const H4U* G1, const H8U& G2, float4_t bg2F, float4_t zero4,
    int gsrc, int q, float& ga, float& gb, float& rs)
{
    float4_t hgLo = MFMA_K16(G1[0].h4, xB, zero4);
    float4_t hgHi = MFMA_K16(G1[1].h4, xB, zero4);
    H8U uh;
    uh.h2[0] = relu2(pkrtz(hgLo[0], hgLo[1]));
    uh.h2[1] = relu2(pkrtz(hgLo[2], hgLo[3]));
    uh.h2[2] = relu2(pkrtz(hgHi[0], hgHi[1]));
    uh.h2[3] = relu2(pkrtz(hgHi[2], hgHi[3]));
    float4_t gl = MFMA_K32(G2.h8, uh.h8, bg2F);
    float ex0 = __builtin_amdgcn_exp2f(gl[0]);
    float ex1 = __builtin_amdgcn_exp2f(gl[1]);
    float ex2 = __builtin_amdgcn_exp2f(gl[2]);
    float ex3 = __builtin_amdgcn_exp2f(gl[3]);
    float s = (ex0 + ex1) + (ex2 + ex3);
    s += __shfl_xor(s, 16);
    rs = __builtin_amdgcn_rcpf(s);
    HI pa, pb;
    pa.h = pkrtz(ex0, ex1);
    pb.h = pkrtz(ex2, ex3);
    int va = __builtin_amdgcn_ds_bpermute(gsrc, pa.i);
    int vb = __builtin_amdgcn_ds_bpermute(gsrc, pb.i);
    HI gsel; gsel.i = (q & 1) ? vb : va;   // lane(q,t): ex[t,2q], ex[t,2q+1]
    ga = (float)gsel.h[0];
    gb = (float)gsel.h[1];
}

__global__ __launch_bounds__(256)
__attribute__((amdgpu_waves_per_eu(3, 3)))
void moe_kernel(
    const float* __restrict__ x,  const float* __restrict__ W1, const float* __restrict__ b1,
    const float* __restrict__ W2, const float* __restrict__ b2, const float* __restrict__ W3,
    const float* __restrict__ b3, const float* __restrict__ Wg1, const float* __restrict__ bg1,
    const float* __restrict__ Wg2, const float* __restrict__ bg2,
    float* __restrict__ out, int nTiles, int tilesPerWave)
{
    const int tid  = threadIdx.x;
    const int lane = tid & 63;
    const int t    = lane & 15;   // token slot
    const int q    = lane >> 4;   // K-quad / row-quad
    const int wv   = tid >> 6;    // wave in block
    const int gw   = (blockIdx.x << 2) + wv;   // global wave id (waves independent in loop)
    const int eo   = t >> 1;      // the ONE expert whose L3 rows this lane holds

    // block-uniform images (every wave reads the same fragments)
    __shared__ W1U  w1img[E_][64];        //  8 KB: [e][lane] -> both L1 A-fragments
    __shared__ H8U  w2img[E_][2][64];     // 16 KB: [e][half][lane] -> L2 A-fragment
    __shared__ float b2f32[E_][H_];       //  1 KB: b2 rows (f32 C-init, broadcast reads)
    __shared__ W1U  g1img[64];            //  1 KB: per-lane gate-L1 fragments
    __shared__ H8U  g2img[64];            //  1 KB: per-lane gate-L2 fragment
    __shared__ H8U  w3img[64];            //  1 KB: per-lane sparse W3 fragment (expert eo)

    const float L2E = 1.44269504f;

    // ---- build expert images: wave wv packs experts {2wv, 2wv+1} (pi layout as R2-R15)
    #pragma unroll
    for (int j = 0; j < 2; ++j) {
        const int e = wv * 2 + j;
        W1U w1v;
        #pragma unroll
        for (int f = 0; f < 2; ++f) {
            float v0 = 0.f, v1 = 0.f, v2 = 0.f, v3 = 0.f;
            const float* We = W1 + (size_t)e * DIN_ * H_ + f * 16 + t;
            if (q == 0)      { v0 = We[0 * H_]; v1 = We[1 * H_]; v2 = We[2 * H_]; v3 = We[3 * H_]; }
            else if (q == 1) { v0 = We[4 * H_]; v1 = We[5 * H_]; v2 = b1[e * H_ + f * 16 + t]; }
            w1v.f[f].h2[0] = pkrtz(v0, v1); w1v.f[f].h2[1] = pkrtz(v2, v3);
        }
        w1img[e][lane] = w1v;
        H8U w2lo, w2hi;
        #pragma unroll
        for (int p = 0; p < 4; ++p) {
            int c0 = ((p >> 1) << 4) + q * 4 + ((p & 1) << 1);
            w2lo.h2[p] = pkrtz(W2[(e * H_ + c0) * H_ + 0  + t], W2[(e * H_ + c0 + 1) * H_ + 0  + t]);
            w2hi.h2[p] = pkrtz(W2[(e * H_ + c0) * H_ + 16 + t], W2[(e * H_ + c0 + 1) * H_ + 16 + t]);
        }
        w2img[e][0][lane] = w2lo;
        w2img[e][1][lane] = w2hi;
        if (lane < H_) b2f32[e][lane] = b2[e * H_ + lane];   // f32 C-init rows
    }

    // ---- wave 0 builds the per-lane gate + W3 images (lane-determined, identical all waves)
    if (wv == 0) {
        W1U g1v;
        #pragma unroll
        for (int f = 0; f < 2; ++f) {
            float v0 = 0.f, v1 = 0.f, v2 = 0.f, v3 = 0.f;
            if (q == 0) {
                v0 = Wg1[0 * H_ + f * 16 + t]; v1 = Wg1[1 * H_ + f * 16 + t];
                v2 = Wg1[2 * H_ + f * 16 + t]; v3 = Wg1[3 * H_ + f * 16 + t];
            } else if (q == 1) {
                v0 = Wg1[4 * H_ + f * 16 + t]; v1 = Wg1[5 * H_ + f * 16 + t];
                v2 = bg1[f * 16 + t];          v3 = 0.f;
            }
            g1v.f[f].h2[0] = pkrtz(v0, v1); g1v.f[f].h2[1] = pkrtz(v2, v3);
        }
        g1img[lane] = g1v;
        H8U g2v, w3v;
        #pragma unroll
        for (int p = 0; p < 4; ++p) {
            int c0 = ((p >> 1) << 4) + q * 4 + ((p & 1) << 1);
            float v0 = (t < E_) ? Wg2[c0 * E_ + t] * L2E : 0.f;
            float v1 = (t < E_) ? Wg2[(c0 + 1) * E_ + t] * L2E : 0.f;
            g2v.h2[p] = pkrtz(v0, v1);
            w3v.h2[p] = pkrtz(W3[(eo * H_ + c0) * 2 + (t & 1)],
                              W3[(eo * H_ + c0 + 1) * 2 + (t & 1)]);
        }
        g2img[lane] = g2v;
        w3img[lane] = w3v;
    }

    // ---- persistent C-inits: bg2 (log2 domain), b3 for all 16 Y rows m=(e,o)
    float4_t bg2F, b3F;
    #pragma unroll
    for (int r = 0; r < 4; ++r) {
        int m = q * 4 + r;
        bg2F[r] = (m < E_) ? bg2[m] * L2E : 0.f;
        b3F[r]  = b3[m];
    }
    const float4_t zero4 = {0.f, 0.f, 0.f, 0.f};
    const int4_t  zeroi  = {0, 0, 0, 0};

    // gate pull: lane(q,t) fetches ex[t,2q],ex[t,2q+1] from lane (q>>1)*16+t
    const int gsrc = ((((q >> 1) << 4) | t) << 2);

    __syncthreads();   // images ready; NO barriers inside the loop

    const int tile0 = gw * tilesPerWave;

    // ---- per-lane x source: quad0 reads x[t][0..3]; quads>=1 read x[t][4..5]
    const int xo1 = (q == 0) ? 0 : 4;
    const int xo2 = (q == 0) ? 2 : 4;
    const float* xq = x + ((size_t)tile0 * 16 + t) * DIN_;
    float2_t la[TB_], lb[TB_];
    #pragma unroll
    for (int u = 0; u < TB_; ++u) {
        la[u] = float2_t{0.f, 0.f};
        lb[u] = float2_t{0.f, 0.f};
        if (tile0 + u < nTiles) {
            la[u] = *(const float2_t*)(xq + (size_t)u * 16 * DIN_ + xo1);
            lb[u] = *(const float2_t*)(xq + (size_t)u * 16 * DIN_ + xo2);
        }
    }

    HI onei; onei.h = pkrtz(1.f, 0.f);
    const bool isq0 = (q == 0);

    // ---- main loop: two tiles per iteration, expert loop software-pipelined
    for (int it = 0; it < tilesPerWave; it += TB_) {
        const int tb = tile0 + it;
        if (tb >= nTiles) break;            // uniform per wave

        // re-read per-lane images each iteration (volatile: must NOT be hoisted to
        // persistent registers -- that would blow the 3-wave arch budget)
        W1U g1v; g1v.i4 = *(const volatile int4_t*)&g1img[lane].i4;
        H8U g2v; g2v.i4 = *(const volatile int4_t*)&g2img[lane].i4;
        H8U w3v; w3v.i4 = *(const volatile int4_t*)&w3img[lane].i4;

        // ---- expert 0's loads issued HERE: their LDS latency hides under the
        //      x-pack + two gate chains below (pipeline prologue)
        W1U w1c  = w1img[0][lane];
        H8U w2loC = w2img[0][0][lane];
        H8U w2hiC = w2img[0][1][lane];
        float4_t b2loC = *(const float4_t*)&b2f32[0][q * 4];
        float4_t b2hiC = *(const float4_t*)&b2f32[0][16 + q * 4];

        // x B-fragments (K=16): q0:(x0..x3) q1:(x4,x5,1,dc) q2/q3: dc (A=0 there)
        H4U ux[TB_];
        #pragma unroll
        for (int u = 0; u < TB_; ++u) {
            ux[u].h2[0] = pkrtz(la[u][0], la[u][1]);
            HI hb; hb.h = pkrtz(lb[u][0], lb[u][1]);
            HI se; se.i = isq0 ? hb.i : onei.i;
            ux[u].h2[1] = se.h;
        }

        // prefetch next pair's x
        if (it + TB_ < tilesPerWave) {
            const float* xn = xq + (size_t)(it + TB_) * 16 * DIN_;
            #pragma unroll
            for (int u = 0; u < TB_; ++u) {
                if (tb + TB_ + u < nTiles) {
                    la[u] = *(const float2_t*)(xn + (size_t)u * 16 * DIN_ + xo1);
                    lb[u] = *(const float2_t*)(xn + (size_t)u * 16 * DIN_ + xo2);
                }
            }
        }

        // gates (once per tile; two independent chains; cover expert-0 load latency)
        float ga[TB_], gb[TB_], rs[TB_];
        #pragma unroll
        for (int u = 0; u < TB_; ++u)
            gate_eval(ux[u].h4, g1v.f, g2v, bg2F, zero4, gsrc, q, ga[u], gb[u], rs[u]);

        // all 8 experts x 2 tiles, software-pipelined: expert e+1's five LDS loads issue
        // before expert e's MFMA chain consumes its (already-arrived) fragments
        float4_t Ya[TB_], Yb[TB_];
        #pragma unroll
        for (int u = 0; u < TB_; ++u) { Ya[u] = b3F; Yb[u] = zero4; }
        #pragma unroll
        for (int e = 0; e < E_; ++e) {
            W1U w1n; H8U w2loN, w2hiN; float4_t b2loN, b2hiN;
            if (e + 1 < E_) {
                w1n   = w1img[e + 1][lane];
                w2loN = w2img[e + 1][0][lane];
                w2hiN = w2img[e + 1][1][lane];
                b2loN = *(const float4_t*)&b2f32[e + 1][q * 4];
                b2hiN = *(const float4_t*)&b2f32[e + 1][16 + q * 4];
            }
            H8U a3;  a3.i4 = (eo == e) ? w3v.i4 : zeroi;   // sparse L3 rows: mask per expert

            #pragma unroll
            for (int u = 0; u < TB_; ++u) {
                float4_t lo = MFMA_K16(w1c.f[0].h4, ux[u].h4, zero4);
                float4_t hi = MFMA_K16(w1c.f[1].h4, ux[u].h4, zero4);
                H8U u1;
                u1.h2[0] = relu2(pkrtz(lo[0], lo[1]));
                u1.h2[1] = relu2(pkrtz(lo[2], lo[3]));
                u1.h2[2] = relu2(pkrtz(hi[0], hi[1]));
                u1.h2[3] = relu2(pkrtz(hi[2], hi[3]));
                float4_t lo2 = MFMA_K32(w2loC.h8, u1.h8, b2loC);   // bias in f32 C-init
                float4_t hi2 = MFMA_K32(w2hiC.h8, u1.h8, b2hiC);
                H8U u2;
                u2.h2[0] = relu2(pkrtz(lo2[0], lo2[1]));
                u2.h2[1] = relu2(pkrtz(lo2[2], lo2[3]));
                u2.h2[2] = relu2(pkrtz(hi2[0], hi2[1]));
                u2.h2[3] = relu2(pkrtz(hi2[2], hi2[3]));
                if (e & 1) Yb[u] = MFMA_K32(a3.h8, u2.h8, Yb[u]);
                else       Ya[u] = MFMA_K32(a3.h8, u2.h8, Ya[u]);
            }

            if (e + 1 < E_) {       // rotate the pipeline buffers (dead copies after unroll)
                w1c = w1n; w2loC = w2loN; w2hiC = w2hiN; b2loC = b2loN; b2hiC = b2hiN;
            }
        }

        // epilogues: lane(q,t) holds Y rows m=4q+r -> experts {2q,2q+1}, o=r&1
        #pragma unroll
        for (int u = 0; u < TB_; ++u) {
            const int tile = tb + u;
            float p0 = ga[u] * (Ya[u][0] + Yb[u][0]) + gb[u] * (Ya[u][2] + Yb[u][2]);
            float p1 = ga[u] * (Ya[u][1] + Yb[u][1]) + gb[u] * (Ya[u][3] + Yb[u][3]);
            p0 += __shfl_xor(p0, 16);
            p0 += __shfl_xor(p0, 32);
            p1 += __shfl_xor(p1, 16);
            p1 += __shfl_xor(p1, 32);
            if (tile < nTiles && lane < 16) {
                float2_t o = {p0 * rs[u], p1 * rs[u]};
                *(float2_t*)(out + ((size_t)tile * 16 + t) * 2) = o;
            }
        }
    }
}

extern "C" void kernel_launch(void* const* d_in, const int* in_sizes, int n_in,
                              void* d_out, int out_size, void* d_ws, size_t ws_size,
                              hipStream_t stream) {
    const float* x   = (const float*)d_in[0];
    const float* W1  = (const float*)d_in[1];
    const float* b1  = (const float*)d_in[2];
    const float* W2  = (const float*)d_in[3];
    const float* b2  = (const float*)d_in[4];
    const float* W3  = (const float*)d_in[5];
    const float* b3  = (const float*)d_in[6];
    const float* Wg1 = (const float*)d_in[7];
    const float* bg1 = (const float*)d_in[8];
    const float* Wg2 = (const float*)d_in[9];
    const float* bg2 = (const float*)d_in[10];
    float* out = (float*)d_out;

    const int B      = in_sizes[0] / DIN_;
    const int nTiles = (B + 15) / 16;
    // waves_per_eu(3,3): arch cap ~85; demand ~68 -> zero spills (measured R16: VGPR 68).
    // 768 blocks x 4 waves = 3072 waves = exact 3 blocks/CU (12 waves/CU), 84 KB LDS/CU.
    // tpw = ceil(65536/3072) = 22; ragged tail handled by per-tile guards.
    const int blocks = 768;
    const int wavesTotal = blocks * 4;
    const int tpw = (nTiles + wavesTotal - 1) / wavesTotal;

    moe_kernel<<<blocks, 256, 0, stream>>>(x, W1, b1, W2, b2, W3, b3,
                                           Wg1, bg1, Wg2, bg2, out, nTiles, tpw);
}